// Round 4
// baseline (147.887 us; speedup 1.0000x reference)
//
#include <hip/hip_runtime.h>
#include <hip/hip_bf16.h>
#include <cstdint>

// LSTM cell, B=16384, IN=512, H=512, fused 4-gate bf16 MFMA GEMM.
// Round 4: free-run schedule (2 barriers/K-tile instead of 8) + persistent
// 2-tile blocks (grid 256 = 1 block/CU, tile-1 epilogue inside the pipeline).

typedef __attribute__((ext_vector_type(8))) __bf16 bf16x8;
typedef __attribute__((ext_vector_type(4))) float f32x4;
typedef __attribute__((address_space(3))) char lds_char;

#define GLOAD_LDS16(gp, lp)                                                        \
    __builtin_amdgcn_global_load_lds(                                              \
        (const __attribute__((address_space(1))) void*)(gp),                       \
        (__attribute__((address_space(3))) void*)(lp), 16, 0, 0)

#define BAR()  asm volatile("s_barrier" ::: "memory")
#define VMW4() asm volatile("s_waitcnt vmcnt(4)" ::: "memory")
#define VMW0() asm volatile("s_waitcnt vmcnt(0)" ::: "memory")
#define LGK0() { asm volatile("s_waitcnt lgkmcnt(0)" ::: "memory");                \
                 __builtin_amdgcn_sched_barrier(0); }
#define DSR(dst, off)                                                              \
    asm volatile("ds_read_b128 %0, %1" : "=v"(dst) : "v"(lds3 + (off)))

__device__ __forceinline__ unsigned short f2bf(float f) {
    unsigned int u = __float_as_uint(f);
    u = (u + 0x7FFFu + ((u >> 16) & 1u)) >> 16;   // RNE
    return (unsigned short)u;
}
__device__ __forceinline__ float tanh_fast(float x) {
    float ax = fabsf(x);
    float e  = __expf(2.f * ax);
    float t  = 1.f - 2.f / (e + 1.f);
    return copysignf(t, x);
}

// ---------------- prepass A (unchanged, verified) ----------------
__global__ __launch_bounds__(256) void conv_a_kernel(const float* __restrict__ x,
                                                     const float* __restrict__ h,
                                                     unsigned short* __restrict__ A) {
    int G  = blockIdx.x * 256 + threadIdx.x;
    int b  = G >> 10;
    int p  = G & 1023;
    int mt = b >> 5;
    int kt = (b >> 1) & 15;
    int ks = b & 1;
    int row = p >> 2;
    int c   = (p & 3) ^ ((row >> 1) & 3);
    int r   = mt * 256 + row;
    int k0  = kt * 64 + ks * 32 + c * 8;
    const float* src = (k0 < 512) ? (x + (size_t)r * 512 + k0)
                                  : (h + (size_t)r * 512 + (k0 - 512));
    const float4* s4 = reinterpret_cast<const float4*>(src);
    float4 v0 = s4[0];
    float4 v1 = s4[1];
    uint4 o;
    o.x = (unsigned)f2bf(v0.x) | ((unsigned)f2bf(v0.y) << 16);
    o.y = (unsigned)f2bf(v0.z) | ((unsigned)f2bf(v0.w) << 16);
    o.z = (unsigned)f2bf(v1.x) | ((unsigned)f2bf(v1.y) << 16);
    o.w = (unsigned)f2bf(v1.z) | ((unsigned)f2bf(v1.w) << 16);
    *reinterpret_cast<uint4*>(A + ((size_t)b * 1024 + p) * 8) = o;
}

// ---------------- prepass B (unchanged, verified) ----------------
__global__ __launch_bounds__(256) void conv_w_kernel(const float* __restrict__ w0,
                                                     const float* __restrict__ w1,
                                                     const float* __restrict__ w2,
                                                     const float* __restrict__ w3,
                                                     unsigned short* __restrict__ Wt) {
    int G  = blockIdx.x * 256 + threadIdx.x;
    int b  = G >> 10;
    int p  = G & 1023;
    int nb = b >> 5;
    int kt = (b >> 1) & 15;
    int ks = b & 1;
    int col = p >> 2;
    int c   = (p & 3) ^ ((col >> 1) & 3);
    int g   = col >> 6;
    int hh  = col & 63;
    int n   = nb * 64 + hh;
    int k0  = kt * 64 + ks * 32 + c * 8;
    const float* Wg = (g == 0) ? w0 : (g == 1) ? w1 : (g == 2) ? w2 : w3;
    unsigned short us[8];
    #pragma unroll
    for (int u = 0; u < 8; ++u) us[u] = f2bf(Wg[(size_t)(k0 + u) * 512 + n]);
    uint4 o;
    o.x = (unsigned)us[0] | ((unsigned)us[1] << 16);
    o.y = (unsigned)us[2] | ((unsigned)us[3] << 16);
    o.z = (unsigned)us[4] | ((unsigned)us[5] << 16);
    o.w = (unsigned)us[6] | ((unsigned)us[7] << 16);
    *reinterpret_cast<uint4*>(Wt + ((size_t)b * 1024 + p) * 8) = o;
}

// ---------------- fused GEMM: persistent 2-tile, free-run schedule ----------------
__global__ __launch_bounds__(512, 2) void lstm_gemm8(
    const char* __restrict__ Apre, const char* __restrict__ Bpre,
    const float* __restrict__ c_cur,
    const float* __restrict__ bi_p, const float* __restrict__ bf_p,
    const float* __restrict__ bo_p, const float* __restrict__ bc_p,
    float* __restrict__ h_out, float* __restrict__ c_out)
{
    extern __shared__ char smem[];
    lds_char* lds3 = (lds_char*)smem;
    const int tid  = threadIdx.x;
    const int lane = tid & 63;
    const int wid  = tid >> 6;
    const int wm   = wid >> 2;
    const int wn   = wid & 3;

    // 256 blocks: xcd = bid&7 -> nb (B panel per XCD, L2-resident);
    // each block does tiles (nb, mt1) then (nb, mt2 = mt1+32).
    const int nb  = blockIdx.x & 7;
    const int mt1 = blockIdx.x >> 3;        // 0..31
    const int mt2 = mt1 + 32;               // 32..63

    const int ar    = lane & 15;
    const int swz   = ((lane >> 4) ^ ((ar >> 1) & 3)) << 4;
    const int aoffb = ar * 64 + swz;
    const int boffb = (wn * 16 + ar) * 64 + swz;
    const int swl   = wid * 1024;

    const char* ApreB1 = Apre + (((size_t)mt1 * 32) << 14) + (size_t)tid * 16;
    const char* ApreB2 = Apre + (((size_t)mt2 * 32) << 14) + (size_t)tid * 16;
    const char* BpreB  = Bpre + (((size_t)nb  * 32) << 14) + (size_t)tid * 16;

#define STAGE_SLICE(gb, ktks, dstb) {                                   \
        const char* gp_ = (gb) + (((size_t)(ktks)) << 14);              \
        GLOAD_LDS16(gp_,        smem + (dstb) + swl);                   \
        GLOAD_LDS16(gp_ + 8192, smem + (dstb) + 8192 + swl); }

    // epilogue constants (hcol identical for both tiles)
    const int r4   = (lane >> 4) * 4;
    const int hcol = nb * 64 + wn * 16 + ar;
    const float bii = bi_p[hcol], bff = bf_p[hcol];
    const float boo = bo_p[hcol], bcc = bc_p[hcol];

    // prologue: stage K-tile 0 of tile 1 (order Aks0, Bks0, Aks1, Bks1)
    STAGE_SLICE(ApreB1, 0, 0);
    STAGE_SLICE(BpreB,  0, 65536);
    STAGE_SLICE(ApreB1, 1, 16384);
    STAGE_SLICE(BpreB,  1, 65536 + 16384);

    f32x4 acc[4][8];
    #pragma unroll
    for (int g = 0; g < 4; ++g)
        #pragma unroll
        for (int m = 0; m < 8; ++m)
            acc[g][m] = (f32x4){0.f, 0.f, 0.f, 0.f};

    bf16x8 aFr[4], bFr[4];

#define LDA(mh, ksb, curb)                                              \
    _Pragma("unroll")                                                   \
    for (int mi = 0; mi < 4; ++mi)                                      \
        DSR(aFr[mi], (curb) + (ksb) +                                   \
            (wm * 8192 + (mh) * 4096 + mi * 1024) + aoffb);
#define LDB(ksb, curb)                                                  \
    _Pragma("unroll")                                                   \
    for (int g = 0; g < 4; ++g)                                         \
        DSR(bFr[g], 65536 + (curb) + (ksb) + g * 4096 + boffb);
#define MM(mh)                                                          \
    _Pragma("unroll")                                                   \
    for (int g = 0; g < 4; ++g)                                         \
        _Pragma("unroll")                                               \
        for (int mi = 0; mi < 4; ++mi)                                  \
            acc[g][(mh) * 4 + mi] = __builtin_amdgcn_mfma_f32_16x16x32_bf16( \
                aFr[mi], bFr[g], acc[g][(mh) * 4 + mi], 0, 0, 0);

#define EPI(mtq) {                                                      \
    _Pragma("unroll")                                                   \
    for (int m = 0; m < 8; ++m) {                                       \
        const int rowb = (mtq) * 256 + wm * 128 + m * 16 + r4;          \
        _Pragma("unroll")                                               \
        for (int rr = 0; rr < 4; ++rr) {                                \
            const size_t o = (size_t)(rowb + rr) * 512 + hcol;          \
            float gi = acc[0][m][rr] + bii;                             \
            float gf = acc[1][m][rr] + bff;                             \
            float go = acc[2][m][rr] + boo;                             \
            float gc = acc[3][m][rr] + bcc;                             \
            float is = 1.f / (1.f + __expf(-gi));                       \
            float fs = 1.f / (1.f + __expf(-gf));                       \
            float os = 1.f / (1.f + __expf(-go));                       \
            float ct = tanh_fast(gc);                                   \
            float cn = fs * c_cur[o] + is * ct;                         \
            h_out[o] = os * tanh_fast(cn);                              \
            c_out[o] = cn;                                              \
        }                                                               \
    } }

    // 32 K-tiles: j 0..15 -> tile 1, 16..31 -> tile 2. Slot = j&1.
    #pragma unroll 1
    for (int j = 0; j < 32; ++j) {
        const int cur  = (j & 1) << 15;
        const int nxt  = cur ^ 32768;
        const int jj   = j + 1;
        const bool more = (j < 31);
        const char* anx = (jj < 16) ? ApreB1 : ApreB2;
        const int ktk2  = (jj & 15) * 2;

        // ---- phase 0: wait+sync for ks0 of K-tile j; stage A-ks0(j+1) ----
        VMW4();
        BAR();
        if (more) STAGE_SLICE(anx, ktk2, nxt);
        if (j == 16) {
            EPI(mt1);
            #pragma unroll
            for (int g = 0; g < 4; ++g)
                #pragma unroll
                for (int m = 0; m < 8; ++m)
                    acc[g][m] = (f32x4){0.f, 0.f, 0.f, 0.f};
        }
        LDA(0, 0, cur); LDB(0, cur);
        LGK0();
        __builtin_amdgcn_s_setprio(1);
        MM(0);
        __builtin_amdgcn_s_setprio(0);

        // ---- phase 1: no barrier; stage B-ks0(j+1) ----
        if (more) STAGE_SLICE(BpreB, ktk2, 65536 + nxt);
        LDA(1, 0, cur);
        LGK0();
        __builtin_amdgcn_s_setprio(1);
        MM(1);
        __builtin_amdgcn_s_setprio(0);

        // ---- phase 2: wait+sync for ks1 of K-tile j; stage A-ks1(j+1) ----
        if (more) { VMW4(); } else { VMW0(); }
        BAR();
        if (more) STAGE_SLICE(anx, ktk2 + 1, 16384 + nxt);
        LDA(0, 16384, cur); LDB(16384, cur);
        LGK0();
        __builtin_amdgcn_s_setprio(1);
        MM(0);
        __builtin_amdgcn_s_setprio(0);

        // ---- phase 3: no barrier; stage B-ks1(j+1) ----
        if (more) STAGE_SLICE(BpreB, ktk2 + 1, 65536 + 16384 + nxt);
        LDA(1, 16384, cur);
        LGK0();
        __builtin_amdgcn_s_setprio(1);
        MM(1);
        __builtin_amdgcn_s_setprio(0);
    }

    // final epilogue (tile 2)
    EPI(mt2);

#undef STAGE_SLICE
#undef LDA
#undef LDB
#undef MM
#undef EPI
}

extern "C" void kernel_launch(void* const* d_in, const int* in_sizes, int n_in,
                              void* d_out, int out_size, void* d_ws, size_t ws_size,
                              hipStream_t stream) {
    const float* x   = (const float*)d_in[0];
    const float* h   = (const float*)d_in[1];
    const float* c   = (const float*)d_in[2];
    const float* W_i = (const float*)d_in[3];
    const float* b_i = (const float*)d_in[4];
    const float* W_f = (const float*)d_in[5];
    const float* b_f = (const float*)d_in[6];
    const float* W_o = (const float*)d_in[7];
    const float* b_o = (const float*)d_in[8];
    const float* W_c = (const float*)d_in[9];
    const float* b_c = (const float*)d_in[10];

    unsigned short* Apre = (unsigned short*)d_ws;
    unsigned short* Bpre = (unsigned short*)((char*)d_ws + 33554432);

    float* h_out = (float*)d_out;
    float* c_out = h_out + (size_t)16384 * 512;

    (void)hipFuncSetAttribute(reinterpret_cast<const void*>(lstm_gemm8),
                              hipFuncAttributeMaxDynamicSharedMemorySize, 131072);

    conv_a_kernel<<<8192, 256, 0, stream>>>(x, h, Apre);
    conv_w_kernel<<<1024, 256, 0, stream>>>(W_i, W_f, W_o, W_c, Bpre);
    lstm_gemm8<<<256, 512, 131072, stream>>>((const char*)Apre, (const char*)Bpre,
                                             c, b_i, b_f, b_o, b_c, h_out, c_out);
}

// Round 5
// 106.792 us; speedup vs baseline: 1.3848x; 1.3848x over previous
//
#include <hip/hip_runtime.h>
#include <hip/hip_bf16.h>
#include <cstdint>

// LSTM cell, B=16384, IN=512, H=512, fused 4-gate bf16 MFMA GEMM.
// Round 5: deep pipeline — BK=32, 4-deep LDS ring (128KB), prefetch 3 K-tiles
// ahead, steady-state vmcnt(8), one barrier per K-tile. Grid 512 (2 gens).

typedef __attribute__((ext_vector_type(8))) __bf16 bf16x8;
typedef __attribute__((ext_vector_type(4))) float f32x4;
typedef __attribute__((address_space(3))) char lds_char;

#define GLOAD_LDS16(gp, lp)                                                        \
    __builtin_amdgcn_global_load_lds(                                              \
        (const __attribute__((address_space(1))) void*)(gp),                       \
        (__attribute__((address_space(3))) void*)(lp), 16, 0, 0)

#define BAR()  asm volatile("s_barrier" ::: "memory")
#define VMW8() asm volatile("s_waitcnt vmcnt(8)" ::: "memory")
#define VMW4() asm volatile("s_waitcnt vmcnt(4)" ::: "memory")
#define VMW0() asm volatile("s_waitcnt vmcnt(0)" ::: "memory")
#define LGK0() { asm volatile("s_waitcnt lgkmcnt(0)" ::: "memory");                \
                 __builtin_amdgcn_sched_barrier(0); }
#define DSR(dst, off)                                                              \
    asm volatile("ds_read_b128 %0, %1" : "=v"(dst) : "v"(lds3 + (off)))

__device__ __forceinline__ unsigned short f2bf(float f) {
    unsigned int u = __float_as_uint(f);
    u = (u + 0x7FFFu + ((u >> 16) & 1u)) >> 16;   // RNE
    return (unsigned short)u;
}
__device__ __forceinline__ float tanh_fast(float x) {
    float ax = fabsf(x);
    float e  = __expf(2.f * ax);
    float t  = 1.f - 2.f / (e + 1.f);
    return copysignf(t, x);
}

// ---------------- prepass A (unchanged, verified) ----------------
// A_pre: [mt=64][32 slices of 16KB]; slice s covers k[s*32, s*32+32).
__global__ __launch_bounds__(256) void conv_a_kernel(const float* __restrict__ x,
                                                     const float* __restrict__ h,
                                                     unsigned short* __restrict__ A) {
    int G  = blockIdx.x * 256 + threadIdx.x;
    int b  = G >> 10;
    int p  = G & 1023;
    int mt = b >> 5;
    int kt = (b >> 1) & 15;
    int ks = b & 1;
    int row = p >> 2;
    int c   = (p & 3) ^ ((row >> 1) & 3);
    int r   = mt * 256 + row;
    int k0  = kt * 64 + ks * 32 + c * 8;
    const float* src = (k0 < 512) ? (x + (size_t)r * 512 + k0)
                                  : (h + (size_t)r * 512 + (k0 - 512));
    const float4* s4 = reinterpret_cast<const float4*>(src);
    float4 v0 = s4[0];
    float4 v1 = s4[1];
    uint4 o;
    o.x = (unsigned)f2bf(v0.x) | ((unsigned)f2bf(v0.y) << 16);
    o.y = (unsigned)f2bf(v0.z) | ((unsigned)f2bf(v0.w) << 16);
    o.z = (unsigned)f2bf(v1.x) | ((unsigned)f2bf(v1.y) << 16);
    o.w = (unsigned)f2bf(v1.z) | ((unsigned)f2bf(v1.w) << 16);
    *reinterpret_cast<uint4*>(A + ((size_t)b * 1024 + p) * 8) = o;
}

// ---------------- prepass B (unchanged, verified) ----------------
__global__ __launch_bounds__(256) void conv_w_kernel(const float* __restrict__ w0,
                                                     const float* __restrict__ w1,
                                                     const float* __restrict__ w2,
                                                     const float* __restrict__ w3,
                                                     unsigned short* __restrict__ Wt) {
    int G  = blockIdx.x * 256 + threadIdx.x;
    int b  = G >> 10;
    int p  = G & 1023;
    int nb = b >> 5;
    int kt = (b >> 1) & 15;
    int ks = b & 1;
    int col = p >> 2;
    int c   = (p & 3) ^ ((col >> 1) & 3);
    int g   = col >> 6;
    int hh  = col & 63;
    int n   = nb * 64 + hh;
    int k0  = kt * 64 + ks * 32 + c * 8;
    const float* Wg = (g == 0) ? w0 : (g == 1) ? w1 : (g == 2) ? w2 : w3;
    unsigned short us[8];
    #pragma unroll
    for (int u = 0; u < 8; ++u) us[u] = f2bf(Wg[(size_t)(k0 + u) * 512 + n]);
    uint4 o;
    o.x = (unsigned)us[0] | ((unsigned)us[1] << 16);
    o.y = (unsigned)us[2] | ((unsigned)us[3] << 16);
    o.z = (unsigned)us[4] | ((unsigned)us[5] << 16);
    o.w = (unsigned)us[6] | ((unsigned)us[7] << 16);
    *reinterpret_cast<uint4*>(Wt + ((size_t)b * 1024 + p) * 8) = o;
}

// ---------------- fused GEMM: BK=32, 4-deep ring, 3-tile prefetch ----------------
__global__ __launch_bounds__(512, 2) void lstm_gemm8(
    const char* __restrict__ Apre, const char* __restrict__ Bpre,
    const float* __restrict__ c_cur,
    const float* __restrict__ bi_p, const float* __restrict__ bf_p,
    const float* __restrict__ bo_p, const float* __restrict__ bc_p,
    float* __restrict__ h_out, float* __restrict__ c_out)
{
    extern __shared__ char smem[];
    lds_char* lds3 = (lds_char*)smem;
    const int tid  = threadIdx.x;
    const int lane = tid & 63;
    const int wid  = tid >> 6;
    const int wm   = wid >> 2;
    const int wn   = wid & 3;

    // 512 blocks, XCD swizzle: nb = bid&7 (B panel per XCD), mt = bid>>3
    const int nb = blockIdx.x & 7;
    const int mt = blockIdx.x >> 3;

    const int ar    = lane & 15;
    const int swz   = ((lane >> 4) ^ ((ar >> 1) & 3)) << 4;
    const int aoffb = ar * 64 + swz;
    const int boffb = (wn * 16 + ar) * 64 + swz;
    const int swl   = wid * 1024;

    const char* ApreB = Apre + (((size_t)mt * 32) << 14) + (size_t)tid * 16;
    const char* BpreB = Bpre + (((size_t)nb * 32) << 14) + (size_t)tid * 16;

    // stage K-tile t (one 16KB A slice + one 16KB B slice) into ring buffer bb
#define STAGE(t, bb) {                                                  \
        const char* ga_ = ApreB + (((size_t)(t)) << 14);                \
        const char* gb_ = BpreB + (((size_t)(t)) << 14);                \
        GLOAD_LDS16(ga_,        smem + (bb) + swl);                     \
        GLOAD_LDS16(ga_ + 8192, smem + (bb) + 8192 + swl);              \
        GLOAD_LDS16(gb_,        smem + (bb) + 16384 + swl);             \
        GLOAD_LDS16(gb_ + 8192, smem + (bb) + 16384 + 8192 + swl); }

    f32x4 acc[4][8];
    #pragma unroll
    for (int g = 0; g < 4; ++g)
        #pragma unroll
        for (int m = 0; m < 8; ++m)
            acc[g][m] = (f32x4){0.f, 0.f, 0.f, 0.f};

    bf16x8 aFr[8], bFr[4];

    // prologue: stage K-tiles 0,1,2 into ring bufs 0,1,2  (12 loads in flight)
    STAGE(0, 0);
    STAGE(1, 32768);
    STAGE(2, 65536);

    #pragma unroll 1
    for (int j = 0; j < 32; ++j) {
        const int buf  = (j & 3) << 15;
        const int bufN = ((j + 3) & 3) << 15;

        // wait: retire current tile's 4 loads (12 -> 8 steady state)
        if (j < 30)      { VMW8(); }
        else if (j == 30){ VMW4(); }
        else             { VMW0(); }
        BAR();

        // stage K-tile j+3 (safe: all waves' reads of bufN retired pre-barrier)
        if (j < 29) STAGE(j + 3, bufN);

        // fragments: A rows wm*128 + mh*64 + mi*16 + ar, k-chunk lane>>4
        #pragma unroll
        for (int mh = 0; mh < 2; ++mh)
            #pragma unroll
            for (int mi = 0; mi < 4; ++mi)
                DSR(aFr[mh * 4 + mi],
                    buf + wm * 8192 + mh * 4096 + mi * 1024 + aoffb);
        #pragma unroll
        for (int g = 0; g < 4; ++g)
            DSR(bFr[g], buf + 16384 + g * 4096 + boffb);

        LGK0();
        __builtin_amdgcn_s_setprio(1);
        #pragma unroll
        for (int g = 0; g < 4; ++g)
            #pragma unroll
            for (int m = 0; m < 8; ++m)
                acc[g][m] = __builtin_amdgcn_mfma_f32_16x16x32_bf16(
                    aFr[m], bFr[g], acc[g][m], 0, 0, 0);
        __builtin_amdgcn_s_setprio(0);
    }

    // fused LSTM epilogue: all 4 gates in-lane
    const int r4   = (lane >> 4) * 4;
    const int hcol = nb * 64 + wn * 16 + ar;
    const float bii = bi_p[hcol], bff = bf_p[hcol];
    const float boo = bo_p[hcol], bcc = bc_p[hcol];
    #pragma unroll
    for (int m = 0; m < 8; ++m) {
        const int rowb = mt * 256 + wm * 128 + m * 16 + r4;
        #pragma unroll
        for (int rr = 0; rr < 4; ++rr) {
            const size_t o = (size_t)(rowb + rr) * 512 + hcol;
            float gi = acc[0][m][rr] + bii;
            float gf = acc[1][m][rr] + bff;
            float go = acc[2][m][rr] + boo;
            float gc = acc[3][m][rr] + bcc;
            float is = 1.f / (1.f + __expf(-gi));
            float fs = 1.f / (1.f + __expf(-gf));
            float os = 1.f / (1.f + __expf(-go));
            float ct = tanh_fast(gc);
            float cn = fs * c_cur[o] + is * ct;
            h_out[o] = os * tanh_fast(cn);
            c_out[o] = cn;
        }
    }
#undef STAGE
}

extern "C" void kernel_launch(void* const* d_in, const int* in_sizes, int n_in,
                              void* d_out, int out_size, void* d_ws, size_t ws_size,
                              hipStream_t stream) {
    const float* x   = (const float*)d_in[0];
    const float* h   = (const float*)d_in[1];
    const float* c   = (const float*)d_in[2];
    const float* W_i = (const float*)d_in[3];
    const float* b_i = (const float*)d_in[4];
    const float* W_f = (const float*)d_in[5];
    const float* b_f = (const float*)d_in[6];
    const float* W_o = (const float*)d_in[7];
    const float* b_o = (const float*)d_in[8];
    const float* W_c = (const float*)d_in[9];
    const float* b_c = (const float*)d_in[10];

    unsigned short* Apre = (unsigned short*)d_ws;
    unsigned short* Bpre = (unsigned short*)((char*)d_ws + 33554432);

    float* h_out = (float*)d_out;
    float* c_out = h_out + (size_t)16384 * 512;

    (void)hipFuncSetAttribute(reinterpret_cast<const void*>(lstm_gemm8),
                              hipFuncAttributeMaxDynamicSharedMemorySize, 131072);

    conv_a_kernel<<<8192, 256, 0, stream>>>(x, h, Apre);
    conv_w_kernel<<<1024, 256, 0, stream>>>(W_i, W_f, W_o, W_c, Bpre);
    lstm_gemm8<<<512, 512, 131072, stream>>>((const char*)Apre, (const char*)Bpre,
                                             c, b_i, b_f, b_o, b_c, h_out, c_out);
}